// Round 1
// baseline (327.810 us; speedup 1.0000x reference)
//
#include <hip/hip_runtime.h>

#define N_NODES 100000
#define N_EDGES 800000
#define H 128
#define N_GRAPHS 500
#define ELL_CAP 32
#define NTILES (N_NODES / 16)   // 6250 row-tiles of 16

typedef __attribute__((ext_vector_type(8))) short bf16x8;   // 8 bf16 = 4 VGPRs
typedef __attribute__((ext_vector_type(4))) float f32x4;

__device__ __forceinline__ unsigned short f2bf(float f) {
    union { float f; unsigned u; } x; x.f = f;
    unsigned r = x.u + 0x7fffu + ((x.u >> 16) & 1u);   // RTNE
    return (unsigned short)(r >> 16);
}

// ---- graph structure build ----------------------------------------------
__global__ void k_init(int* cnt, int* fill) {
    int i = blockIdx.x * 256 + threadIdx.x;
    if (i < N_NODES) { cnt[i] = 0; fill[i] = 0; }
}

__global__ void k_count(const int* dst, const int* mask, int* cnt) {
    int e = blockIdx.x * 256 + threadIdx.x;
    if (e < N_EDGES && mask[e]) atomicAdd(&cnt[dst[e]], 1);
}

__global__ void k_dinv(const int* cnt, float* dinv) {
    int i = blockIdx.x * 256 + threadIdx.x;
    if (i < N_NODES) dinv[i] = rsqrtf(1.0f + (float)cnt[i]);
}

__global__ void k_fill(const int* src, const int* dst, const int* mask,
                       const float* dinv, int* fill, int* ell_src, float* ell_coef) {
    int e = blockIdx.x * 256 + threadIdx.x;
    if (e < N_EDGES && mask[e]) {
        int d = dst[e], s = src[e];
        int p = atomicAdd(&fill[d], 1);
        if (p < ELL_CAP) {
            ell_src[d * ELL_CAP + p]  = s;
            ell_coef[d * ELL_CAP + p] = dinv[s] * dinv[d];
        }
    }
}

// ---- embedding gather (fp32 table -> bf16 feature matrix) ----------------
__global__ void k_embed(const int* z, const float* zt, unsigned short* xb) {
    int t = blockIdx.x * 256 + threadIdx.x;           // N*32 threads, 4 elem each
    if (t >= N_NODES * 32) return;
    int n = t >> 5, q = t & 31;
    float4 v = *(const float4*)(zt + (size_t)z[n] * H + q * 4);
    ushort4 o;
    o.x = f2bf(v.x); o.y = f2bf(v.y); o.z = f2bf(v.z); o.w = f2bf(v.w);
    *(ushort4*)(xb + (size_t)n * H + q * 4) = o;
}

// ---- pack W[128][128] fp32 into bf16 MFMA B-fragment order ---------------
// Wp[((c*4+kt)*64+lane)*8 + j] = bf16( W[kt*32 + (lane>>4)*8 + j][c*16 + (lane&15)] )
__global__ void k_packw(const float* W, unsigned short* Wp) {
    int t = blockIdx.x * 256 + threadIdx.x;   // 2048 lane-frags
    if (t >= 2048) return;
    int lane = t & 63, kt = (t >> 6) & 3, c = t >> 8;
    int quad = lane >> 4, n = c * 16 + (lane & 15);
    unsigned short o[8];
#pragma unroll
    for (int j = 0; j < 8; j++) {
        int k = kt * 32 + quad * 8 + j;
        o[j] = f2bf(W[k * H + n]);
    }
    ushort4 lo, hi;
    lo.x = o[0]; lo.y = o[1]; lo.z = o[2]; lo.w = o[3];
    hi.x = o[4]; hi.y = o[5]; hi.z = o[6]; hi.w = o[7];
    *(ushort4*)(Wp + t * 8)     = lo;
    *(ushort4*)(Wp + t * 8 + 4) = hi;
}

// ---- xw = xb @ W  (bf16 MFMA, fp32 out). One wave per 16-row tile. -------
__global__ __launch_bounds__(256) void k_gemm(const unsigned short* xb,
                                              const unsigned short* Wp, float* xw) {
    int lane = threadIdx.x & 63, wv = threadIdx.x >> 6;
    int t = blockIdx.x * 4 + wv;
    if (t >= NTILES) return;
    int m = lane & 15, quad = lane >> 4;

    const unsigned short* ar = xb + (size_t)(t * 16 + m) * H + quad * 8;
    bf16x8 a0 = *(const bf16x8*)(ar);
    bf16x8 a1 = *(const bf16x8*)(ar + 32);
    bf16x8 a2 = *(const bf16x8*)(ar + 64);
    bf16x8 a3 = *(const bf16x8*)(ar + 96);

    f32x4 acc[8];
#pragma unroll
    for (int c = 0; c < 8; c++) acc[c] = (f32x4){0.f, 0.f, 0.f, 0.f};

#pragma unroll
    for (int c = 0; c < 8; c++) {
        const unsigned short* bp = Wp + ((size_t)(c * 4) * 64 + lane) * 8;
        bf16x8 b0 = *(const bf16x8*)(bp);
        bf16x8 b1 = *(const bf16x8*)(bp + 64 * 8);
        bf16x8 b2 = *(const bf16x8*)(bp + 128 * 8);
        bf16x8 b3 = *(const bf16x8*)(bp + 192 * 8);
        acc[c] = __builtin_amdgcn_mfma_f32_16x16x32_bf16(a0, b0, acc[c], 0, 0, 0);
        acc[c] = __builtin_amdgcn_mfma_f32_16x16x32_bf16(a1, b1, acc[c], 0, 0, 0);
        acc[c] = __builtin_amdgcn_mfma_f32_16x16x32_bf16(a2, b2, acc[c], 0, 0, 0);
        acc[c] = __builtin_amdgcn_mfma_f32_16x16x32_bf16(a3, b3, acc[c], 0, 0, 0);
    }

    int r0 = t * 16 + quad * 4;
#pragma unroll
    for (int c = 0; c < 8; c++)
#pragma unroll
        for (int i = 0; i < 4; i++)
            xw[(size_t)(r0 + i) * H + c * 16 + m] = acc[c][i];
}

// ---- aggregation: out[v] = relu( dinv[v]^2*xw[v] + sum coef*xw[src] + b )
// one wave per node, 2 floats per lane; output bf16 (feeds next GEMM)
__global__ __launch_bounds__(256) void k_agg(const float* xw, const int* ell_src,
                                             const float* ell_coef, const int* cnt,
                                             const float* dinv, const float* bias,
                                             unsigned short* out) {
    int lane = threadIdx.x & 63, wv = threadIdx.x >> 6;
    int v = blockIdx.x * 4 + wv;
    if (v >= N_NODES) return;
    int l2 = lane * 2;
    float dv = dinv[v], sc = dv * dv;
    float2 xs = *(const float2*)(xw + (size_t)v * H + l2);
    float ax = sc * xs.x + bias[l2];
    float ay = sc * xs.y + bias[l2 + 1];
    int n = cnt[v]; if (n > ELL_CAP) n = ELL_CAP;
    const int*   es = ell_src  + (size_t)v * ELL_CAP;
    const float* ec = ell_coef + (size_t)v * ELL_CAP;
    for (int k = 0; k < n; k++) {
        int s = es[k]; float cf = ec[k];
        float2 mr = *(const float2*)(xw + (size_t)s * H + l2);
        ax += cf * mr.x; ay += cf * mr.y;
    }
    ax = fmaxf(ax, 0.f); ay = fmaxf(ay, 0.f);
    ushort2 o; o.x = f2bf(ax); o.y = f2bf(ay);
    *(ushort2*)(out + (size_t)v * H + l2) = o;
}

// ---- layer-2 aggregation only at center nodes (200g, 200g+1), fp32, no relu
__global__ __launch_bounds__(256) void k_aggc(const float* xw, const int* ell_src,
                                              const float* ell_coef, const int* cnt,
                                              const float* dinv, const float* bias,
                                              float* cbuf) {
    int lane = threadIdx.x & 63, wv = threadIdx.x >> 6;
    int idx = blockIdx.x * 4 + wv;
    if (idx >= 2 * N_GRAPHS) return;
    int v = (idx >> 1) * 200 + (idx & 1);
    int l2 = lane * 2;
    float dv = dinv[v], sc = dv * dv;
    float2 xs = *(const float2*)(xw + (size_t)v * H + l2);
    float ax = sc * xs.x + bias[l2];
    float ay = sc * xs.y + bias[l2 + 1];
    int n = cnt[v]; if (n > ELL_CAP) n = ELL_CAP;
    const int*   es = ell_src  + (size_t)v * ELL_CAP;
    const float* ec = ell_coef + (size_t)v * ELL_CAP;
    for (int k = 0; k < n; k++) {
        int s = es[k]; float cf = ec[k];
        float2 mr = *(const float2*)(xw + (size_t)s * H + l2);
        ax += cf * mr.x; ay += cf * mr.y;
    }
    cbuf[(size_t)idx * H + l2]     = ax;
    cbuf[(size_t)idx * H + l2 + 1] = ay;
}

// ---- hadamard pool + MLP head -------------------------------------------
__global__ __launch_bounds__(128) void k_mlp(const float* cbuf, const float* l1w,
                                             const float* l1b, const float* l2w,
                                             const float* l2b, float* out) {
    __shared__ float p[H];
    __shared__ float red[H];
    int g = blockIdx.x, j = threadIdx.x;
    p[j] = cbuf[(size_t)(2 * g) * H + j] * cbuf[(size_t)(2 * g + 1) * H + j];
    __syncthreads();
    float h = l1b[j];
#pragma unroll 8
    for (int k = 0; k < H; k++) h += p[k] * l1w[k * H + j];
    h = fmaxf(h, 0.f);
    red[j] = h * l2w[j];
    __syncthreads();
    for (int s = 64; s > 0; s >>= 1) {
        if (j < s) red[j] += red[j + s];
        __syncthreads();
    }
    if (j == 0) out[g] = red[0] + l2b[0];
}

extern "C" void kernel_launch(void* const* d_in, const int* in_sizes, int n_in,
                              void* d_out, int out_size, void* d_ws, size_t ws_size,
                              hipStream_t stream) {
    const int*   z      = (const int*)d_in[0];
    const int*   esrc   = (const int*)d_in[1];
    const int*   edst   = ((const int*)d_in[1]) + N_EDGES;
    const int*   mask   = (const int*)d_in[3];
    const float* ztab   = (const float*)d_in[4];
    const float* W0     = (const float*)d_in[5];
    const float* b0     = (const float*)d_in[6];
    const float* W1     = (const float*)d_in[7];
    const float* b1     = (const float*)d_in[8];
    const float* W2     = (const float*)d_in[9];
    const float* b2     = (const float*)d_in[10];
    const float* l1w    = (const float*)d_in[11];
    const float* l1b    = (const float*)d_in[12];
    const float* l2w    = (const float*)d_in[13];
    const float* l2b    = (const float*)d_in[14];
    float* out = (float*)d_out;

    char* w = (char*)d_ws;
    size_t o = 0;
    auto carve = [&](size_t bytes) { char* p = w + o; o = (o + bytes + 255) & ~(size_t)255; return p; };
    unsigned short* xb       = (unsigned short*)carve((size_t)N_NODES * H * 2);
    float*          xw       = (float*)carve((size_t)N_NODES * H * 4);
    int*            cnt      = (int*)carve((size_t)N_NODES * 4);
    int*            fill     = (int*)carve((size_t)N_NODES * 4);
    float*          dinv     = (float*)carve((size_t)N_NODES * 4);
    int*            ell_src  = (int*)carve((size_t)N_NODES * ELL_CAP * 4);
    float*          ell_coef = (float*)carve((size_t)N_NODES * ELL_CAP * 4);
    float*          cbuf     = (float*)carve((size_t)2 * N_GRAPHS * H * 4);
    unsigned short* Wp0      = (unsigned short*)carve(16384 * 2);
    unsigned short* Wp1      = (unsigned short*)carve(16384 * 2);
    unsigned short* Wp2      = (unsigned short*)carve(16384 * 2);

    int gn = (N_NODES + 255) / 256;        // 391
    int ge = (N_EDGES + 255) / 256;        // 3125

    k_init <<<gn, 256, 0, stream>>>(cnt, fill);
    k_count<<<ge, 256, 0, stream>>>(edst, mask, cnt);
    k_dinv <<<gn, 256, 0, stream>>>(cnt, dinv);
    k_fill <<<ge, 256, 0, stream>>>(esrc, edst, mask, dinv, fill, ell_src, ell_coef);

    k_embed<<<(N_NODES * 32 + 255) / 256, 256, 0, stream>>>(z, ztab, xb);
    k_packw<<<8, 256, 0, stream>>>(W0, Wp0);
    k_packw<<<8, 256, 0, stream>>>(W1, Wp1);
    k_packw<<<8, 256, 0, stream>>>(W2, Wp2);

    int gt = (NTILES + 3) / 4;             // 1563
    int gv = (N_NODES + 3) / 4;            // 25000

    // layer 0
    k_gemm<<<gt, 256, 0, stream>>>(xb, Wp0, xw);
    k_agg <<<gv, 256, 0, stream>>>(xw, ell_src, ell_coef, cnt, dinv, b0, xb);
    // layer 1
    k_gemm<<<gt, 256, 0, stream>>>(xb, Wp1, xw);
    k_agg <<<gv, 256, 0, stream>>>(xw, ell_src, ell_coef, cnt, dinv, b1, xb);
    // layer 2 (aggregate only at the 1000 center nodes)
    k_gemm<<<gt, 256, 0, stream>>>(xb, Wp2, xw);
    k_aggc<<<(2 * N_GRAPHS + 3) / 4, 256, 0, stream>>>(xw, ell_src, ell_coef, cnt, dinv, b2, cbuf);

    k_mlp<<<N_GRAPHS, 128, 0, stream>>>(cbuf, l1w, l1b, l2w, l2b, out);
}

// Round 2
// 311.265 us; speedup vs baseline: 1.0532x; 1.0532x over previous
//
#include <hip/hip_runtime.h>

#define N_NODES 100000
#define N_EDGES 800000
#define H 128
#define N_GRAPHS 500
#define ELL_CAP 32
#define NTILES (N_NODES / 16)   // 6250 row-tiles of 16
#define NC_ROWS 1008            // 1000 center rows padded to 16-multiple
#define NC_TILES (NC_ROWS / 16) // 63

typedef __attribute__((ext_vector_type(8))) short bf16x8;   // 8 bf16 = 4 VGPRs
typedef __attribute__((ext_vector_type(4))) float f32x4;

__device__ __forceinline__ unsigned short f2bf(float f) {
    union { float f; unsigned u; } x; x.f = f;
    unsigned r = x.u + 0x7fffu + ((x.u >> 16) & 1u);   // RTNE
    return (unsigned short)(r >> 16);
}
__device__ __forceinline__ float bf2f(unsigned short u) {
    return __uint_as_float((unsigned)u << 16);
}

// ---- graph structure build ----------------------------------------------
__global__ void k_init(int* cnt, int* fill) {
    int i = blockIdx.x * 256 + threadIdx.x;
    if (i < N_NODES) { cnt[i] = 0; fill[i] = 0; }
}

__global__ void k_count(const int* dst, const int* mask, int* cnt) {
    int e = blockIdx.x * 256 + threadIdx.x;
    if (e < N_EDGES && mask[e]) atomicAdd(&cnt[dst[e]], 1);
}

__global__ void k_dinv(const int* cnt, float* dinv) {
    int i = blockIdx.x * 256 + threadIdx.x;
    if (i < N_NODES) dinv[i] = rsqrtf(1.0f + (float)cnt[i]);
}

// ELL rows of interleaved (src, coef) pairs — one line covers a whole row
__global__ void k_fill(const int* src, const int* dst, const int* mask,
                       const float* dinv, int* fill, int2* pairs) {
    int e = blockIdx.x * 256 + threadIdx.x;
    if (e < N_EDGES && mask[e]) {
        int d = dst[e], s = src[e];
        int p = atomicAdd(&fill[d], 1);
        if (p < ELL_CAP)
            pairs[(size_t)d * ELL_CAP + p] = make_int2(s, __float_as_int(dinv[s] * dinv[d]));
    }
}

// ---- pack W[128][128] fp32 into bf16 MFMA B-fragment order ---------------
__global__ void k_packw(const float* W, unsigned short* Wp) {
    int t = blockIdx.x * 256 + threadIdx.x;   // 2048 lane-frags
    if (t >= 2048) return;
    int lane = t & 63, kt = (t >> 6) & 3, c = t >> 8;
    int quad = lane >> 4, n = c * 16 + (lane & 15);
    unsigned short o[8];
#pragma unroll
    for (int j = 0; j < 8; j++) {
        int k = kt * 32 + quad * 8 + j;
        o[j] = f2bf(W[k * H + n]);
    }
    ushort4 lo, hi;
    lo.x = o[0]; lo.y = o[1]; lo.z = o[2]; lo.w = o[3];
    hi.x = o[4]; hi.y = o[5]; hi.z = o[6]; hi.w = o[7];
    *(ushort4*)(Wp + t * 8)     = lo;
    *(ushort4*)(Wp + t * 8 + 4) = hi;
}

// ---- layer-0 aggregation straight from the embedding table ---------------
// y[v] = dinv[v]^2 * tab[z[v]] + sum coef * tab[z[src]]   (bf16 out)
__global__ __launch_bounds__(256) void k_agg0(const int* z, const float* tab,
                                              const int2* pairs, const int* cnt,
                                              const float* dinv, unsigned short* y) {
    int lane = threadIdx.x & 63, wv = threadIdx.x >> 6;
    int v = blockIdx.x * 4 + wv;
    if (v >= N_NODES) return;
    int l2 = lane * 2;
    float dv = dinv[v], sc = dv * dv;
    float2 xs = *(const float2*)(tab + (size_t)z[v] * H + l2);
    float ax = sc * xs.x, ay = sc * xs.y;
    int n = cnt[v]; if (n > ELL_CAP) n = ELL_CAP;
    const int2* pr = pairs + (size_t)v * ELL_CAP;
    for (int k = 0; k < n; k++) {
        int2 p = pr[k];
        float cf = __int_as_float(p.y);
        float2 mr = *(const float2*)(tab + (size_t)z[p.x] * H + l2);
        ax += cf * mr.x; ay += cf * mr.y;
    }
    ushort2 o; o.x = f2bf(ax); o.y = f2bf(ay);
    *(ushort2*)(y + (size_t)v * H + l2) = o;
}

// ---- aggregation over bf16 features: y[v] = sc*x[v] + sum coef*x[src] ----
__global__ __launch_bounds__(256) void k_agg(const unsigned short* xb,
                                             const int2* pairs, const int* cnt,
                                             const float* dinv, unsigned short* y) {
    int lane = threadIdx.x & 63, wv = threadIdx.x >> 6;
    int v = blockIdx.x * 4 + wv;
    if (v >= N_NODES) return;
    int l2 = lane * 2;
    float dv = dinv[v], sc = dv * dv;
    ushort2 xs = *(const ushort2*)(xb + (size_t)v * H + l2);
    float ax = sc * bf2f(xs.x), ay = sc * bf2f(xs.y);
    int n = cnt[v]; if (n > ELL_CAP) n = ELL_CAP;
    const int2* pr = pairs + (size_t)v * ELL_CAP;
    for (int k = 0; k < n; k++) {
        int2 p = pr[k];
        float cf = __int_as_float(p.y);
        ushort2 mr = *(const ushort2*)(xb + (size_t)p.x * H + l2);
        ax += cf * bf2f(mr.x); ay += cf * bf2f(mr.y);
    }
    ushort2 o; o.x = f2bf(ax); o.y = f2bf(ay);
    *(ushort2*)(y + (size_t)v * H + l2) = o;
}

// ---- layer-2 aggregation only at the 1000 center nodes (rows padded) -----
__global__ __launch_bounds__(256) void k_aggc(const unsigned short* xb,
                                              const int2* pairs, const int* cnt,
                                              const float* dinv, unsigned short* yc) {
    int lane = threadIdx.x & 63, wv = threadIdx.x >> 6;
    int idx = blockIdx.x * 4 + wv;
    if (idx >= NC_ROWS) return;
    int l2 = lane * 2;
    if (idx >= 2 * N_GRAPHS) {           // zero the 8 pad rows
        *(ushort2*)(yc + (size_t)idx * H + l2) = make_ushort2(0, 0);
        return;
    }
    int v = (idx >> 1) * 200 + (idx & 1);
    float dv = dinv[v], sc = dv * dv;
    ushort2 xs = *(const ushort2*)(xb + (size_t)v * H + l2);
    float ax = sc * bf2f(xs.x), ay = sc * bf2f(xs.y);
    int n = cnt[v]; if (n > ELL_CAP) n = ELL_CAP;
    const int2* pr = pairs + (size_t)v * ELL_CAP;
    for (int k = 0; k < n; k++) {
        int2 p = pr[k];
        float cf = __int_as_float(p.y);
        ushort2 mr = *(const ushort2*)(xb + (size_t)p.x * H + l2);
        ax += cf * bf2f(mr.x); ay += cf * bf2f(mr.y);
    }
    ushort2 o; o.x = f2bf(ax); o.y = f2bf(ay);
    *(ushort2*)(yc + (size_t)idx * H + l2) = o;
}

// ---- out = act(y @ W + b): bf16 MFMA, fused bias (+ReLU), bf16/fp32 out --
template<bool RELU, bool BF16OUT>
__global__ __launch_bounds__(256) void k_gemm(const unsigned short* ybuf,
                                              const unsigned short* Wp,
                                              const float* bias, void* outp,
                                              int ntiles, int maxrow) {
    int lane = threadIdx.x & 63, wv = threadIdx.x >> 6;
    int t = blockIdx.x * 4 + wv;
    if (t >= ntiles) return;
    int m = lane & 15, quad = lane >> 4;

    const unsigned short* ar = ybuf + (size_t)(t * 16 + m) * H + quad * 8;
    bf16x8 a0 = *(const bf16x8*)(ar);
    bf16x8 a1 = *(const bf16x8*)(ar + 32);
    bf16x8 a2 = *(const bf16x8*)(ar + 64);
    bf16x8 a3 = *(const bf16x8*)(ar + 96);

    f32x4 acc[8];
#pragma unroll
    for (int c = 0; c < 8; c++) acc[c] = (f32x4){0.f, 0.f, 0.f, 0.f};

#pragma unroll
    for (int c = 0; c < 8; c++) {
        const unsigned short* bp = Wp + ((size_t)(c * 4) * 64 + lane) * 8;
        bf16x8 b0 = *(const bf16x8*)(bp);
        bf16x8 b1 = *(const bf16x8*)(bp + 64 * 8);
        bf16x8 b2 = *(const bf16x8*)(bp + 128 * 8);
        bf16x8 b3 = *(const bf16x8*)(bp + 192 * 8);
        acc[c] = __builtin_amdgcn_mfma_f32_16x16x32_bf16(a0, b0, acc[c], 0, 0, 0);
        acc[c] = __builtin_amdgcn_mfma_f32_16x16x32_bf16(a1, b1, acc[c], 0, 0, 0);
        acc[c] = __builtin_amdgcn_mfma_f32_16x16x32_bf16(a2, b2, acc[c], 0, 0, 0);
        acc[c] = __builtin_amdgcn_mfma_f32_16x16x32_bf16(a3, b3, acc[c], 0, 0, 0);
    }

    int r0 = t * 16 + quad * 4;
#pragma unroll
    for (int c = 0; c < 8; c++) {
        float bv = bias[c * 16 + m];
#pragma unroll
        for (int i = 0; i < 4; i++) {
            int r = r0 + i;
            if (r < maxrow) {
                float val = acc[c][i] + bv;
                if (RELU) val = fmaxf(val, 0.f);
                if (BF16OUT)
                    ((unsigned short*)outp)[(size_t)r * H + c * 16 + m] = f2bf(val);
                else
                    ((float*)outp)[(size_t)r * H + c * 16 + m] = val;
            }
        }
    }
}

// ---- hadamard pool + MLP head -------------------------------------------
__global__ __launch_bounds__(128) void k_mlp(const float* cbuf, const float* l1w,
                                             const float* l1b, const float* l2w,
                                             const float* l2b, float* out) {
    __shared__ float p[H];
    __shared__ float red[H];
    int g = blockIdx.x, j = threadIdx.x;
    p[j] = cbuf[(size_t)(2 * g) * H + j] * cbuf[(size_t)(2 * g + 1) * H + j];
    __syncthreads();
    float h = l1b[j];
#pragma unroll 8
    for (int k = 0; k < H; k++) h += p[k] * l1w[k * H + j];
    h = fmaxf(h, 0.f);
    red[j] = h * l2w[j];
    __syncthreads();
    for (int s = 64; s > 0; s >>= 1) {
        if (j < s) red[j] += red[j + s];
        __syncthreads();
    }
    if (j == 0) out[g] = red[0] + l2b[0];
}

extern "C" void kernel_launch(void* const* d_in, const int* in_sizes, int n_in,
                              void* d_out, int out_size, void* d_ws, size_t ws_size,
                              hipStream_t stream) {
    const int*   z    = (const int*)d_in[0];
    const int*   esrc = (const int*)d_in[1];
    const int*   edst = ((const int*)d_in[1]) + N_EDGES;
    const int*   mask = (const int*)d_in[3];
    const float* ztab = (const float*)d_in[4];
    const float* W0   = (const float*)d_in[5];
    const float* b0   = (const float*)d_in[6];
    const float* W1   = (const float*)d_in[7];
    const float* b1   = (const float*)d_in[8];
    const float* W2   = (const float*)d_in[9];
    const float* b2   = (const float*)d_in[10];
    const float* l1w  = (const float*)d_in[11];
    const float* l1b  = (const float*)d_in[12];
    const float* l2w  = (const float*)d_in[13];
    const float* l2b  = (const float*)d_in[14];
    float* out = (float*)d_out;

    char* w = (char*)d_ws;
    size_t o = 0;
    auto carve = [&](size_t bytes) { char* p = w + o; o = (o + bytes + 255) & ~(size_t)255; return p; };
    unsigned short* xb    = (unsigned short*)carve((size_t)N_NODES * H * 2);
    unsigned short* y     = (unsigned short*)carve((size_t)N_NODES * H * 2);
    unsigned short* yc    = (unsigned short*)carve((size_t)NC_ROWS * H * 2);
    int*            cnt   = (int*)carve((size_t)N_NODES * 4);
    int*            fill  = (int*)carve((size_t)N_NODES * 4);
    float*          dinv  = (float*)carve((size_t)N_NODES * 4);
    int2*           pairs = (int2*)carve((size_t)N_NODES * ELL_CAP * 8);
    float*          cbuf  = (float*)carve((size_t)2 * N_GRAPHS * H * 4);
    unsigned short* Wp0   = (unsigned short*)carve(16384 * 2);
    unsigned short* Wp1   = (unsigned short*)carve(16384 * 2);
    unsigned short* Wp2   = (unsigned short*)carve(16384 * 2);

    int gn = (N_NODES + 255) / 256;        // 391
    int ge = (N_EDGES + 255) / 256;        // 3125

    k_init <<<gn, 256, 0, stream>>>(cnt, fill);
    k_count<<<ge, 256, 0, stream>>>(edst, mask, cnt);
    k_dinv <<<gn, 256, 0, stream>>>(cnt, dinv);
    k_fill <<<ge, 256, 0, stream>>>(esrc, edst, mask, dinv, fill, pairs);

    k_packw<<<8, 256, 0, stream>>>(W0, Wp0);
    k_packw<<<8, 256, 0, stream>>>(W1, Wp1);
    k_packw<<<8, 256, 0, stream>>>(W2, Wp2);

    int gv = (N_NODES + 3) / 4;            // 25000 blocks (1 wave/node)
    int gt = (NTILES + 3) / 4;             // 1563

    // layer 0: aggregate from embedding table, then fused GEMM+bias+ReLU
    k_agg0<<<gv, 256, 0, stream>>>(z, ztab, pairs, cnt, dinv, y);
    k_gemm<true, true><<<gt, 256, 0, stream>>>(y, Wp0, b0, xb, NTILES, N_NODES);
    // layer 1
    k_agg <<<gv, 256, 0, stream>>>(xb, pairs, cnt, dinv, y);
    k_gemm<true, true><<<gt, 256, 0, stream>>>(y, Wp1, b1, xb, NTILES, N_NODES);
    // layer 2: aggregate only at 1000 center nodes, tiny GEMM (fp32 out, no relu)
    k_aggc<<<(NC_ROWS + 3) / 4, 256, 0, stream>>>(xb, pairs, cnt, dinv, yc);
    k_gemm<false, false><<<(NC_TILES + 3) / 4, 256, 0, stream>>>(yc, Wp2, b2, cbuf, NC_TILES, 2 * N_GRAPHS);

    k_mlp<<<N_GRAPHS, 128, 0, stream>>>(cbuf, l1w, l1b, l2w, l2b, out);
}

// Round 3
// 220.851 us; speedup vs baseline: 1.4843x; 1.4094x over previous
//
#include <hip/hip_runtime.h>

#define N_NODES 100000
#define N_EDGES 800000
#define H 128
#define N_GRAPHS 500
#define ELL_CAP 32
#define MAXC1 33000             // count1 <= 1000 centers * (1+ELL_CAP)
#define NC_ROWS 1008            // 1000 center rows padded to 16-multiple

typedef __attribute__((ext_vector_type(8))) short bf16x8;   // 8 bf16 = 4 VGPRs
typedef __attribute__((ext_vector_type(4))) float f32x4;

__device__ __forceinline__ unsigned short f2bf(float f) {
    union { float f; unsigned u; } x; x.f = f;
    unsigned r = x.u + 0x7fffu + ((x.u >> 16) & 1u);   // RTNE
    return (unsigned short)(r >> 16);
}
__device__ __forceinline__ float bf2f(unsigned short u) {
    return __uint_as_float((unsigned)u << 16);
}
__device__ __forceinline__ bool is_center(int v) { return (v % 200) < 2; }

// ---- init: zero counters, seed flags with centers ------------------------
__global__ void k_init(int* cnt, int* fill, unsigned char* f0, unsigned char* f1,
                       int* ctrs) {
    int i = blockIdx.x * 256 + threadIdx.x;
    if (i < N_NODES) {
        cnt[i] = 0; fill[i] = 0;
        unsigned char c = is_center(i) ? 1 : 0;
        f0[i] = c; f1[i] = c;
    }
    if (i < 2) ctrs[i] = 0;
}

// ---- edge scan 1: degree count + flag1 (srcs feeding centers) ------------
__global__ void k_scan1(const int* src, const int* dst, const int* mask,
                        int* cnt, unsigned char* f1) {
    int e = blockIdx.x * 256 + threadIdx.x;
    if (e < N_EDGES && mask[e]) {
        int d = dst[e];
        atomicAdd(&cnt[d], 1);
        if (is_center(d)) f1[src[e]] = 1;
    }
}

__global__ void k_dinv(const int* cnt, float* dinv) {
    int i = blockIdx.x * 256 + threadIdx.x;
    if (i < N_NODES) dinv[i] = rsqrtf(1.0f + (float)cnt[i]);
}

// ---- edge scan 2: flag0 (srcs feeding N1) --------------------------------
__global__ void k_flag0(const int* src, const int* dst, const int* mask,
                        const unsigned char* f1, unsigned char* f0) {
    int e = blockIdx.x * 256 + threadIdx.x;
    if (e < N_EDGES && mask[e]) {
        int d = dst[e];
        if (f1[d]) f0[src[e]] = 1;
    }
}

// ---- edge scan 3: build ELL (src,coef) pairs, only for needed dsts -------
__global__ void k_fill(const int* src, const int* dst, const int* mask,
                       const float* dinv, const unsigned char* f0,
                       const unsigned char* f1, int* fill, int2* pairs) {
    int e = blockIdx.x * 256 + threadIdx.x;
    if (e < N_EDGES && mask[e]) {
        int d = dst[e];
        if (f0[d] | f1[d]) {
            int s = src[e];
            int p = atomicAdd(&fill[d], 1);
            if (p < ELL_CAP)
                pairs[(size_t)d * ELL_CAP + p] =
                    make_int2(s, __float_as_int(dinv[s] * dinv[d]));
        }
    }
}

// ---- compaction: list0 = N0 (union f0,f1), list1 = N1 --------------------
__global__ void k_compact(const unsigned char* f0, const unsigned char* f1,
                          int* list0, int* list1, int* ctrs) {
    int v = blockIdx.x * 256 + threadIdx.x;
    if (v >= N_NODES) return;
    unsigned char a1 = f1[v];
    unsigned char a0 = f0[v] | a1;
    if (a0) { int i = atomicAdd(&ctrs[0], 1); list0[i] = v; }
    if (a1) { int j = atomicAdd(&ctrs[1], 1); list1[j] = v; }
}

// ---- pack W[128][128] fp32 into bf16 MFMA B-fragment order ---------------
__global__ void k_packw(const float* W, unsigned short* Wp) {
    int t = blockIdx.x * 256 + threadIdx.x;   // 2048 lane-frags
    if (t >= 2048) return;
    int lane = t & 63, kt = (t >> 6) & 3, c = t >> 8;
    int quad = lane >> 4, n = c * 16 + (lane & 15);
    unsigned short o[8];
#pragma unroll
    for (int j = 0; j < 8; j++) {
        int k = kt * 32 + quad * 8 + j;
        o[j] = f2bf(W[k * H + n]);
    }
    ushort4 lo, hi;
    lo.x = o[0]; lo.y = o[1]; lo.z = o[2]; lo.w = o[3];
    hi.x = o[4]; hi.y = o[5]; hi.z = o[6]; hi.w = o[7];
    *(ushort4*)(Wp + t * 8)     = lo;
    *(ushort4*)(Wp + t * 8 + 4) = hi;
}

// ---- layer-0 aggregation from embedding table, compacted rows ------------
__global__ __launch_bounds__(256) void k_agg0(const int* z, const float* tab,
                                              const int2* pairs, const int* cnt,
                                              const float* dinv, const int* list,
                                              const int* countp, unsigned short* y) {
    int lane = threadIdx.x & 63, wv = threadIdx.x >> 6;
    int i = blockIdx.x * 4 + wv;
    if (i >= *countp) return;
    int v = list[i];
    int l2 = lane * 2;
    int n = cnt[v]; if (n > ELL_CAP) n = ELL_CAP;
    const int2* pr = pairs + (size_t)v * ELL_CAP;
    int2 myp = (lane < n) ? pr[lane] : make_int2(0, 0);   // lanes 0..31 hold row
    int px = myp.x; float pc = __int_as_float(myp.y);
    float dv = dinv[v], sc = dv * dv;
    float2 xs = *(const float2*)(tab + (size_t)z[v] * H + l2);
    float ax = sc * xs.x, ay = sc * xs.y;
    int k = 0;
    for (; k + 3 < n; k += 4) {     // 4 gathers in flight per chain step
        int s0 = __shfl(px, k),   s1 = __shfl(px, k+1);
        int s2 = __shfl(px, k+2), s3 = __shfl(px, k+3);
        float c0 = __shfl(pc, k),   c1 = __shfl(pc, k+1);
        float c2 = __shfl(pc, k+2), c3 = __shfl(pc, k+3);
        int z0 = z[s0], z1 = z[s1], z2 = z[s2], z3 = z[s3];
        float2 m0 = *(const float2*)(tab + (size_t)z0 * H + l2);
        float2 m1 = *(const float2*)(tab + (size_t)z1 * H + l2);
        float2 m2 = *(const float2*)(tab + (size_t)z2 * H + l2);
        float2 m3 = *(const float2*)(tab + (size_t)z3 * H + l2);
        ax += c0 * m0.x + c1 * m1.x + c2 * m2.x + c3 * m3.x;
        ay += c0 * m0.y + c1 * m1.y + c2 * m2.y + c3 * m3.y;
    }
    for (; k < n; k++) {
        int s = __shfl(px, k); float c = __shfl(pc, k);
        int zz = z[s];
        float2 m = *(const float2*)(tab + (size_t)zz * H + l2);
        ax += c * m.x; ay += c * m.y;
    }
    ushort2 o; o.x = f2bf(ax); o.y = f2bf(ay);
    *(ushort2*)(y + (size_t)i * H + l2) = o;
}

// ---- mid-layer aggregation over bf16 features, compacted rows ------------
__global__ __launch_bounds__(256) void k_agg(const unsigned short* xb,
                                             const int2* pairs, const int* cnt,
                                             const float* dinv, const int* list,
                                             const int* countp, unsigned short* y) {
    int lane = threadIdx.x & 63, wv = threadIdx.x >> 6;
    int i = blockIdx.x * 4 + wv;
    if (i >= *countp) return;
    int v = list[i];
    int l2 = lane * 2;
    int n = cnt[v]; if (n > ELL_CAP) n = ELL_CAP;
    const int2* pr = pairs + (size_t)v * ELL_CAP;
    int2 myp = (lane < n) ? pr[lane] : make_int2(0, 0);
    int px = myp.x; float pc = __int_as_float(myp.y);
    float dv = dinv[v], sc = dv * dv;
    ushort2 xs = *(const ushort2*)(xb + (size_t)v * H + l2);
    float ax = sc * bf2f(xs.x), ay = sc * bf2f(xs.y);
    int k = 0;
    for (; k + 3 < n; k += 4) {
        int s0 = __shfl(px, k),   s1 = __shfl(px, k+1);
        int s2 = __shfl(px, k+2), s3 = __shfl(px, k+3);
        float c0 = __shfl(pc, k),   c1 = __shfl(pc, k+1);
        float c2 = __shfl(pc, k+2), c3 = __shfl(pc, k+3);
        ushort2 m0 = *(const ushort2*)(xb + (size_t)s0 * H + l2);
        ushort2 m1 = *(const ushort2*)(xb + (size_t)s1 * H + l2);
        ushort2 m2 = *(const ushort2*)(xb + (size_t)s2 * H + l2);
        ushort2 m3 = *(const ushort2*)(xb + (size_t)s3 * H + l2);
        ax += c0 * bf2f(m0.x) + c1 * bf2f(m1.x) + c2 * bf2f(m2.x) + c3 * bf2f(m3.x);
        ay += c0 * bf2f(m0.y) + c1 * bf2f(m1.y) + c2 * bf2f(m2.y) + c3 * bf2f(m3.y);
    }
    for (; k < n; k++) {
        int s = __shfl(px, k); float c = __shfl(pc, k);
        ushort2 m = *(const ushort2*)(xb + (size_t)s * H + l2);
        ax += c * bf2f(m.x); ay += c * bf2f(m.y);
    }
    ushort2 o; o.x = f2bf(ax); o.y = f2bf(ay);
    *(ushort2*)(y + (size_t)i * H + l2) = o;
}

// ---- layer-2 aggregation only at the 1000 center nodes -------------------
__global__ __launch_bounds__(256) void k_aggc(const unsigned short* xb,
                                              const int2* pairs, const int* cnt,
                                              const float* dinv, unsigned short* yc) {
    int lane = threadIdx.x & 63, wv = threadIdx.x >> 6;
    int idx = blockIdx.x * 4 + wv;
    if (idx >= NC_ROWS) return;
    int l2 = lane * 2;
    if (idx >= 2 * N_GRAPHS) {           // zero the 8 pad rows
        *(ushort2*)(yc + (size_t)idx * H + l2) = make_ushort2(0, 0);
        return;
    }
    int v = (idx >> 1) * 200 + (idx & 1);
    int n = cnt[v]; if (n > ELL_CAP) n = ELL_CAP;
    const int2* pr = pairs + (size_t)v * ELL_CAP;
    int2 myp = (lane < n) ? pr[lane] : make_int2(0, 0);
    int px = myp.x; float pc = __int_as_float(myp.y);
    float dv = dinv[v], sc = dv * dv;
    ushort2 xs = *(const ushort2*)(xb + (size_t)v * H + l2);
    float ax = sc * bf2f(xs.x), ay = sc * bf2f(xs.y);
    int k = 0;
    for (; k + 3 < n; k += 4) {
        int s0 = __shfl(px, k),   s1 = __shfl(px, k+1);
        int s2 = __shfl(px, k+2), s3 = __shfl(px, k+3);
        float c0 = __shfl(pc, k),   c1 = __shfl(pc, k+1);
        float c2 = __shfl(pc, k+2), c3 = __shfl(pc, k+3);
        ushort2 m0 = *(const ushort2*)(xb + (size_t)s0 * H + l2);
        ushort2 m1 = *(const ushort2*)(xb + (size_t)s1 * H + l2);
        ushort2 m2 = *(const ushort2*)(xb + (size_t)s2 * H + l2);
        ushort2 m3 = *(const ushort2*)(xb + (size_t)s3 * H + l2);
        ax += c0 * bf2f(m0.x) + c1 * bf2f(m1.x) + c2 * bf2f(m2.x) + c3 * bf2f(m3.x);
        ay += c0 * bf2f(m0.y) + c1 * bf2f(m1.y) + c2 * bf2f(m2.y) + c3 * bf2f(m3.y);
    }
    for (; k < n; k++) {
        int s = __shfl(px, k); float c = __shfl(pc, k);
        ushort2 m = *(const ushort2*)(xb + (size_t)s * H + l2);
        ax += c * bf2f(m.x); ay += c * bf2f(m.y);
    }
    ushort2 o; o.x = f2bf(ax); o.y = f2bf(ay);
    *(ushort2*)(yc + (size_t)idx * H + l2) = o;
}

// ---- out = act(y @ W + b): bf16 MFMA, optional indirect scatter store ----
template<bool RELU, bool BF16OUT, bool INDIRECT>
__global__ __launch_bounds__(256) void k_gemm(const unsigned short* ybuf,
                                              const unsigned short* Wp,
                                              const float* bias, void* outp,
                                              const int* list, const int* countp,
                                              int fixedRows) {
    int rows = INDIRECT ? *countp : fixedRows;
    int lane = threadIdx.x & 63, wv = threadIdx.x >> 6;
    int t = blockIdx.x * 4 + wv;
    int ntiles = (rows + 15) >> 4;
    if (t >= ntiles) return;
    int m = lane & 15, quad = lane >> 4;

    const unsigned short* ar = ybuf + (size_t)(t * 16 + m) * H + quad * 8;
    bf16x8 a0 = *(const bf16x8*)(ar);
    bf16x8 a1 = *(const bf16x8*)(ar + 32);
    bf16x8 a2 = *(const bf16x8*)(ar + 64);
    bf16x8 a3 = *(const bf16x8*)(ar + 96);

    f32x4 acc[8];
#pragma unroll
    for (int c = 0; c < 8; c++) acc[c] = (f32x4){0.f, 0.f, 0.f, 0.f};

#pragma unroll
    for (int c = 0; c < 8; c++) {
        const unsigned short* bp = Wp + ((size_t)(c * 4) * 64 + lane) * 8;
        bf16x8 b0 = *(const bf16x8*)(bp);
        bf16x8 b1 = *(const bf16x8*)(bp + 64 * 8);
        bf16x8 b2 = *(const bf16x8*)(bp + 128 * 8);
        bf16x8 b3 = *(const bf16x8*)(bp + 192 * 8);
        acc[c] = __builtin_amdgcn_mfma_f32_16x16x32_bf16(a0, b0, acc[c], 0, 0, 0);
        acc[c] = __builtin_amdgcn_mfma_f32_16x16x32_bf16(a1, b1, acc[c], 0, 0, 0);
        acc[c] = __builtin_amdgcn_mfma_f32_16x16x32_bf16(a2, b2, acc[c], 0, 0, 0);
        acc[c] = __builtin_amdgcn_mfma_f32_16x16x32_bf16(a3, b3, acc[c], 0, 0, 0);
    }

    int r0 = t * 16 + quad * 4;
    int rid[4];
#pragma unroll
    for (int i = 0; i < 4; i++) {
        int r = r0 + i;
        rid[i] = (r < rows) ? (INDIRECT ? list[r] : r) : -1;
    }
#pragma unroll
    for (int c = 0; c < 8; c++) {
        float bv = bias[c * 16 + m];
#pragma unroll
        for (int i = 0; i < 4; i++) {
            if (rid[i] >= 0) {
                float val = acc[c][i] + bv;
                if (RELU) val = fmaxf(val, 0.f);
                if (BF16OUT)
                    ((unsigned short*)outp)[(size_t)rid[i] * H + c * 16 + m] = f2bf(val);
                else
                    ((float*)outp)[(size_t)rid[i] * H + c * 16 + m] = val;
            }
        }
    }
}

// ---- hadamard pool + MLP head -------------------------------------------
__global__ __launch_bounds__(128) void k_mlp(const float* cbuf, const float* l1w,
                                             const float* l1b, const float* l2w,
                                             const float* l2b, float* out) {
    __shared__ float p[H];
    __shared__ float red[H];
    int g = blockIdx.x, j = threadIdx.x;
    p[j] = cbuf[(size_t)(2 * g) * H + j] * cbuf[(size_t)(2 * g + 1) * H + j];
    __syncthreads();
    float h = l1b[j];
#pragma unroll 8
    for (int k = 0; k < H; k++) h += p[k] * l1w[k * H + j];
    h = fmaxf(h, 0.f);
    red[j] = h * l2w[j];
    __syncthreads();
    for (int s = 64; s > 0; s >>= 1) {
        if (j < s) red[j] += red[j + s];
        __syncthreads();
    }
    if (j == 0) out[g] = red[0] + l2b[0];
}

extern "C" void kernel_launch(void* const* d_in, const int* in_sizes, int n_in,
                              void* d_out, int out_size, void* d_ws, size_t ws_size,
                              hipStream_t stream) {
    const int*   z    = (const int*)d_in[0];
    const int*   esrc = (const int*)d_in[1];
    const int*   edst = ((const int*)d_in[1]) + N_EDGES;
    const int*   mask = (const int*)d_in[3];
    const float* ztab = (const float*)d_in[4];
    const float* W0   = (const float*)d_in[5];
    const float* b0   = (const float*)d_in[6];
    const float* W1   = (const float*)d_in[7];
    const float* b1   = (const float*)d_in[8];
    const float* W2   = (const float*)d_in[9];
    const float* b2   = (const float*)d_in[10];
    const float* l1w  = (const float*)d_in[11];
    const float* l1b  = (const float*)d_in[12];
    const float* l2w  = (const float*)d_in[13];
    const float* l2b  = (const float*)d_in[14];
    float* out = (float*)d_out;

    char* w = (char*)d_ws;
    size_t o = 0;
    auto carve = [&](size_t bytes) { char* p = w + o; o = (o + bytes + 255) & ~(size_t)255; return p; };
    unsigned short* xb    = (unsigned short*)carve((size_t)N_NODES * H * 2);
    unsigned short* y     = (unsigned short*)carve((size_t)N_NODES * H * 2);
    unsigned short* yc    = (unsigned short*)carve((size_t)NC_ROWS * H * 2);
    int*            cnt   = (int*)carve((size_t)N_NODES * 4);
    int*            fill  = (int*)carve((size_t)N_NODES * 4);
    float*          dinv  = (float*)carve((size_t)N_NODES * 4);
    int2*           pairs = (int2*)carve((size_t)N_NODES * ELL_CAP * 8);
    float*          cbuf  = (float*)carve((size_t)2 * N_GRAPHS * H * 4);
    unsigned char*  f0    = (unsigned char*)carve(N_NODES);
    unsigned char*  f1    = (unsigned char*)carve(N_NODES);
    int*            list0 = (int*)carve((size_t)N_NODES * 4);
    int*            list1 = (int*)carve((size_t)N_NODES * 4);
    int*            ctrs  = (int*)carve(256);
    unsigned short* Wp0   = (unsigned short*)carve(16384 * 2);
    unsigned short* Wp1   = (unsigned short*)carve(16384 * 2);
    unsigned short* Wp2   = (unsigned short*)carve(16384 * 2);

    int gn = (N_NODES + 255) / 256;        // 391
    int ge = (N_EDGES + 255) / 256;        // 3125

    k_init   <<<gn, 256, 0, stream>>>(cnt, fill, f0, f1, ctrs);
    k_scan1  <<<ge, 256, 0, stream>>>(esrc, edst, mask, cnt, f1);
    k_dinv   <<<gn, 256, 0, stream>>>(cnt, dinv);
    k_flag0  <<<ge, 256, 0, stream>>>(esrc, edst, mask, f1, f0);
    k_fill   <<<ge, 256, 0, stream>>>(esrc, edst, mask, dinv, f0, f1, fill, pairs);
    k_compact<<<gn, 256, 0, stream>>>(f0, f1, list0, list1, ctrs);

    k_packw<<<8, 256, 0, stream>>>(W0, Wp0);
    k_packw<<<8, 256, 0, stream>>>(W1, Wp1);
    k_packw<<<8, 256, 0, stream>>>(W2, Wp2);

    // worst-case grids with device-count early exit (grids must be static)
    int g_agg0  = (N_NODES + 3) / 4;                    // 25000
    int g_gemm0 = (N_NODES / 16 + 3) / 4;               // 1563
    int g_agg1  = (MAXC1 + 3) / 4;                      // 8250
    int g_gemm1 = (((MAXC1 + 15) / 16) + 3) / 4;        // 516

    // layer 0: aggregate (compacted N0) then GEMM+bias+ReLU, scatter to xb
    k_agg0<<<g_agg0, 256, 0, stream>>>(z, ztab, pairs, cnt, dinv, list0, &ctrs[0], y);
    k_gemm<true, true, true><<<g_gemm0, 256, 0, stream>>>(y, Wp0, b0, xb, list0, &ctrs[0], 0);
    // layer 1: aggregate (compacted N1) then GEMM+bias+ReLU, scatter to xb
    k_agg <<<g_agg1, 256, 0, stream>>>(xb, pairs, cnt, dinv, list1, &ctrs[1], y);
    k_gemm<true, true, true><<<g_gemm1, 256, 0, stream>>>(y, Wp1, b1, xb, list1, &ctrs[1], 0);
    // layer 2: aggregate at 1000 centers, tiny GEMM (fp32 out, no relu)
    k_aggc<<<(NC_ROWS + 3) / 4, 256, 0, stream>>>(xb, pairs, cnt, dinv, yc);
    k_gemm<false, false, false><<<(NC_ROWS / 16 + 3) / 4, 256, 0, stream>>>(yc, Wp2, b2, cbuf, nullptr, nullptr, 2 * N_GRAPHS);

    k_mlp<<<N_GRAPHS, 128, 0, stream>>>(cbuf, l1w, l1b, l2w, l2b, out);
}

// Round 4
// 200.610 us; speedup vs baseline: 1.6341x; 1.1009x over previous
//
#include <hip/hip_runtime.h>

#define N_NODES 100000
#define N_EDGES 800000
#define H 128
#define N_GRAPHS 500
#define ELL_CAP 32
#define EB 782                   // edge blocks: ceil(800000/4/256)
#define NB 391                   // node blocks: ceil(100000/256)
#define MAXC1 33008              // count1 <= 1000*(1+32), padded to 16
#define NC_ROWS 1008             // 1000 center rows padded to 16

typedef __attribute__((ext_vector_type(8))) short bf16x8;
typedef __attribute__((ext_vector_type(4))) float f32x4;

__device__ __forceinline__ unsigned short f2bf(float f) {
    union { float f; unsigned u; } x; x.f = f;
    unsigned r = x.u + 0x7fffu + ((x.u >> 16) & 1u);   // RTNE
    return (unsigned short)(r >> 16);
}
__device__ __forceinline__ float bf2f(unsigned short u) {
    return __uint_as_float((unsigned)u << 16);
}
__device__ __forceinline__ bool is_center(int v) { return (v % 200) < 2; }

// ---- init ----------------------------------------------------------------
__global__ void k_init(int* cnt, int* fill, unsigned char* f0, unsigned char* f1,
                       int* ctrs) {
    int i = blockIdx.x * 256 + threadIdx.x;
    if (i < N_NODES) {
        cnt[i] = 0; fill[i] = 0;
        unsigned char c = is_center(i) ? 1 : 0;
        f0[i] = c; f1[i] = c;
    }
    if (i < 2) ctrs[i] = 0;
}

// ---- edge scan 1: degree count + flag1 (srcs feeding centers), x4 vector -
__global__ void k_scan1(const int4* src4, const int4* dst4, const int4* mask4,
                        int* cnt, unsigned char* f1) {
    int i = blockIdx.x * 256 + threadIdx.x;
    if (i >= N_EDGES / 4) return;
    int4 s = src4[i], d = dst4[i], mk = mask4[i];
    if (mk.x) { atomicAdd(&cnt[d.x], 1); if (is_center(d.x)) f1[s.x] = 1; }
    if (mk.y) { atomicAdd(&cnt[d.y], 1); if (is_center(d.y)) f1[s.y] = 1; }
    if (mk.z) { atomicAdd(&cnt[d.z], 1); if (is_center(d.z)) f1[s.z] = 1; }
    if (mk.w) { atomicAdd(&cnt[d.w], 1); if (is_center(d.w)) f1[s.w] = 1; }
}

// ---- edge scan 2: flag0 (srcs feeding N1) --------------------------------
__global__ void k_flag0(const int4* src4, const int4* dst4, const int4* mask4,
                        const unsigned char* f1, unsigned char* f0) {
    int i = blockIdx.x * 256 + threadIdx.x;
    if (i >= N_EDGES / 4) return;
    int4 s = src4[i], d = dst4[i], mk = mask4[i];
    if (mk.x && f1[d.x]) f0[s.x] = 1;
    if (mk.y && f1[d.y]) f0[s.y] = 1;
    if (mk.z && f1[d.z]) f0[s.z] = 1;
    if (mk.w && f1[d.w]) f0[s.w] = 1;
}

// ---- edge pass (blocks 0..EB-1): ELL fill for N0 dsts;
//      node pass (blocks EB..): compact list0/list1 ------------------------
__global__ void k_fillcompact(const int4* src4, const int4* dst4, const int4* mask4,
                              const int* cnt, const unsigned char* f0,
                              const unsigned char* f1, int* fill, int2* pairs,
                              int* list0, int* list1, int* ctrs) {
    int b = blockIdx.x;
    if (b < EB) {
        int i = b * 256 + threadIdx.x;
        if (i >= N_EDGES / 4) return;
        int4 s4 = src4[i], d4 = dst4[i], mk = mask4[i];
        int ss[4] = { s4.x, s4.y, s4.z, s4.w };
        int dd[4] = { d4.x, d4.y, d4.z, d4.w };
        int mm[4] = { mk.x, mk.y, mk.z, mk.w };
#pragma unroll
        for (int q = 0; q < 4; q++) {
            if (!mm[q]) continue;
            int d = dd[q];
            if (f0[d] | f1[d]) {
                int s = ss[q];
                int p = atomicAdd(&fill[d], 1);
                if (p < ELL_CAP) {
                    float coef = rsqrtf(1.0f + (float)cnt[s]) *
                                 rsqrtf(1.0f + (float)cnt[d]);
                    pairs[(size_t)d * ELL_CAP + p] = make_int2(s, __float_as_int(coef));
                }
            }
        }
    } else {
        int v = (b - EB) * 256 + threadIdx.x;
        if (v >= N_NODES) return;
        unsigned char a1 = f1[v];
        unsigned char a0 = f0[v] | a1;
        if (a0) { int i = atomicAdd(&ctrs[0], 1); list0[i] = v; }
        if (a1) { int j = atomicAdd(&ctrs[1], 1); list1[j] = v; }
    }
}

// ---- pack all 3 W[128][128] fp32 into bf16 MFMA B-fragment order ---------
__global__ void k_packw(const float* W0, const float* W1, const float* W2,
                        unsigned short* Wp) {
    int wi = blockIdx.x >> 3;
    const float* W = (wi == 0) ? W0 : (wi == 1) ? W1 : W2;
    int t = (blockIdx.x & 7) * 256 + threadIdx.x;   // 0..2047
    int lane = t & 63, kt = (t >> 6) & 3, c = t >> 8;
    int quad = lane >> 4, n = c * 16 + (lane & 15);
    unsigned short o[8];
#pragma unroll
    for (int j = 0; j < 8; j++)
        o[j] = f2bf(W[(kt * 32 + quad * 8 + j) * H + n]);
    ushort4 lo = { o[0], o[1], o[2], o[3] }, hi = { o[4], o[5], o[6], o[7] };
    unsigned short* dst = Wp + (size_t)wi * 16384 + (size_t)t * 8;
    *(ushort4*)(dst)     = lo;
    *(ushort4*)(dst + 4) = hi;
}

// ---- fused layer A: agg from z-table + GEMM + bias + ReLU + scatter bf16 -
__global__ __launch_bounds__(256) void k_layerA(const int* z, const float* tab,
                                                const int2* pairs, const int* cnt,
                                                const int* list, const int* countp,
                                                const unsigned short* Wp,
                                                const float* bias,
                                                unsigned short* xb) {
    __shared__ unsigned short yt[16][136];
    int count = *countp;
    int t = blockIdx.x;
    if (t * 16 >= count) return;
    int tid = threadIdx.x, lane = tid & 63, wv = tid >> 6;
    int l2 = lane * 2;

    for (int q = 0; q < 4; q++) {
        int r = t * 16 + wv * 4 + q;
        float ax = 0.f, ay = 0.f;
        if (r < count) {
            int v = list[r];
            int n = cnt[v]; if (n > ELL_CAP) n = ELL_CAP;
            const int2* pr = pairs + (size_t)v * ELL_CAP;
            int2 myp = (lane < n) ? pr[lane] : make_int2(0, 0);
            int px = myp.x; float pc = __int_as_float(myp.y);
            float dv = rsqrtf(1.0f + (float)n);
            float sc = dv * dv;
            float2 xs = *(const float2*)(tab + (size_t)z[v] * H + l2);
            ax = sc * xs.x; ay = sc * xs.y;
            int k = 0;
            for (; k + 3 < n; k += 4) {
                int s0 = __shfl(px, k),   s1 = __shfl(px, k + 1);
                int s2 = __shfl(px, k + 2), s3 = __shfl(px, k + 3);
                float c0 = __shfl(pc, k),   c1 = __shfl(pc, k + 1);
                float c2 = __shfl(pc, k + 2), c3 = __shfl(pc, k + 3);
                int z0 = z[s0], z1 = z[s1], z2 = z[s2], z3 = z[s3];
                float2 m0 = *(const float2*)(tab + (size_t)z0 * H + l2);
                float2 m1 = *(const float2*)(tab + (size_t)z1 * H + l2);
                float2 m2 = *(const float2*)(tab + (size_t)z2 * H + l2);
                float2 m3 = *(const float2*)(tab + (size_t)z3 * H + l2);
                ax += c0 * m0.x + c1 * m1.x + c2 * m2.x + c3 * m3.x;
                ay += c0 * m0.y + c1 * m1.y + c2 * m2.y + c3 * m3.y;
            }
            for (; k < n; k++) {
                int s = __shfl(px, k); float c = __shfl(pc, k);
                float2 m = *(const float2*)(tab + (size_t)z[s] * H + l2);
                ax += c * m.x; ay += c * m.y;
            }
        }
        ushort2 o; o.x = f2bf(ax); o.y = f2bf(ay);
        *(ushort2*)&yt[wv * 4 + q][l2] = o;
    }
    __syncthreads();

    int m = lane & 15, quad = lane >> 4;
    bf16x8 a0 = *(const bf16x8*)&yt[m][quad * 8];
    bf16x8 a1 = *(const bf16x8*)&yt[m][32 + quad * 8];
    bf16x8 a2 = *(const bf16x8*)&yt[m][64 + quad * 8];
    bf16x8 a3 = *(const bf16x8*)&yt[m][96 + quad * 8];

    f32x4 acc[2];
#pragma unroll
    for (int c2 = 0; c2 < 2; c2++) {
        int c = wv * 2 + c2;
        const unsigned short* bp = Wp + ((size_t)(c * 4) * 64 + lane) * 8;
        bf16x8 b0 = *(const bf16x8*)(bp);
        bf16x8 b1 = *(const bf16x8*)(bp + 64 * 8);
        bf16x8 b2 = *(const bf16x8*)(bp + 128 * 8);
        bf16x8 b3 = *(const bf16x8*)(bp + 192 * 8);
        f32x4 a = (f32x4){0.f, 0.f, 0.f, 0.f};
        a = __builtin_amdgcn_mfma_f32_16x16x32_bf16(a0, b0, a, 0, 0, 0);
        a = __builtin_amdgcn_mfma_f32_16x16x32_bf16(a1, b1, a, 0, 0, 0);
        a = __builtin_amdgcn_mfma_f32_16x16x32_bf16(a2, b2, a, 0, 0, 0);
        a = __builtin_amdgcn_mfma_f32_16x16x32_bf16(a3, b3, a, 0, 0, 0);
        acc[c2] = a;
    }

    int r0 = t * 16 + quad * 4;
    int rid[4];
#pragma unroll
    for (int i = 0; i < 4; i++) {
        int r = r0 + i;
        rid[i] = (r < count) ? list[r] : -1;
    }
#pragma unroll
    for (int c2 = 0; c2 < 2; c2++) {
        int col = (wv * 2 + c2) * 16 + m;
        float bv = bias[col];
#pragma unroll
        for (int i = 0; i < 4; i++)
            if (rid[i] >= 0)
                xb[(size_t)rid[i] * H + col] = f2bf(fmaxf(acc[c2][i] + bv, 0.f));
    }
}

// ---- fused layer B: agg from bf16 xb + GEMM + bias + ReLU + scatter ------
__global__ __launch_bounds__(256) void k_layerB(const unsigned short* xin,
                                                const int2* pairs, const int* cnt,
                                                const int* list, const int* countp,
                                                const unsigned short* Wp,
                                                const float* bias,
                                                unsigned short* xb) {
    __shared__ unsigned short yt[16][136];
    int count = *countp;
    int t = blockIdx.x;
    if (t * 16 >= count) return;
    int tid = threadIdx.x, lane = tid & 63, wv = tid >> 6;
    int l2 = lane * 2;

    for (int q = 0; q < 4; q++) {
        int r = t * 16 + wv * 4 + q;
        float ax = 0.f, ay = 0.f;
        if (r < count) {
            int v = list[r];
            int n = cnt[v]; if (n > ELL_CAP) n = ELL_CAP;
            const int2* pr = pairs + (size_t)v * ELL_CAP;
            int2 myp = (lane < n) ? pr[lane] : make_int2(0, 0);
            int px = myp.x; float pc = __int_as_float(myp.y);
            float dv = rsqrtf(1.0f + (float)n);
            float sc = dv * dv;
            ushort2 xs = *(const ushort2*)(xin + (size_t)v * H + l2);
            ax = sc * bf2f(xs.x); ay = sc * bf2f(xs.y);
            int k = 0;
            for (; k + 3 < n; k += 4) {
                int s0 = __shfl(px, k),   s1 = __shfl(px, k + 1);
                int s2 = __shfl(px, k + 2), s3 = __shfl(px, k + 3);
                float c0 = __shfl(pc, k),   c1 = __shfl(pc, k + 1);
                float c2 = __shfl(pc, k + 2), c3 = __shfl(pc, k + 3);
                ushort2 m0 = *(const ushort2*)(xin + (size_t)s0 * H + l2);
                ushort2 m1 = *(const ushort2*)(xin + (size_t)s1 * H + l2);
                ushort2 m2 = *(const ushort2*)(xin + (size_t)s2 * H + l2);
                ushort2 m3 = *(const ushort2*)(xin + (size_t)s3 * H + l2);
                ax += c0 * bf2f(m0.x) + c1 * bf2f(m1.x) + c2 * bf2f(m2.x) + c3 * bf2f(m3.x);
                ay += c0 * bf2f(m0.y) + c1 * bf2f(m1.y) + c2 * bf2f(m2.y) + c3 * bf2f(m3.y);
            }
            for (; k < n; k++) {
                int s = __shfl(px, k); float c = __shfl(pc, k);
                ushort2 m = *(const ushort2*)(xin + (size_t)s * H + l2);
                ax += c * bf2f(m.x); ay += c * bf2f(m.y);
            }
        }
        ushort2 o; o.x = f2bf(ax); o.y = f2bf(ay);
        *(ushort2*)&yt[wv * 4 + q][l2] = o;
    }
    __syncthreads();

    int m = lane & 15, quad = lane >> 4;
    bf16x8 a0 = *(const bf16x8*)&yt[m][quad * 8];
    bf16x8 a1 = *(const bf16x8*)&yt[m][32 + quad * 8];
    bf16x8 a2 = *(const bf16x8*)&yt[m][64 + quad * 8];
    bf16x8 a3 = *(const bf16x8*)&yt[m][96 + quad * 8];

    f32x4 acc[2];
#pragma unroll
    for (int c2 = 0; c2 < 2; c2++) {
        int c = wv * 2 + c2;
        const unsigned short* bp = Wp + ((size_t)(c * 4) * 64 + lane) * 8;
        bf16x8 b0 = *(const bf16x8*)(bp);
        bf16x8 b1 = *(const bf16x8*)(bp + 64 * 8);
        bf16x8 b2 = *(const bf16x8*)(bp + 128 * 8);
        bf16x8 b3 = *(const bf16x8*)(bp + 192 * 8);
        f32x4 a = (f32x4){0.f, 0.f, 0.f, 0.f};
        a = __builtin_amdgcn_mfma_f32_16x16x32_bf16(a0, b0, a, 0, 0, 0);
        a = __builtin_amdgcn_mfma_f32_16x16x32_bf16(a1, b1, a, 0, 0, 0);
        a = __builtin_amdgcn_mfma_f32_16x16x32_bf16(a2, b2, a, 0, 0, 0);
        a = __builtin_amdgcn_mfma_f32_16x16x32_bf16(a3, b3, a, 0, 0, 0);
        acc[c2] = a;
    }

    int r0 = t * 16 + quad * 4;
    int rid[4];
#pragma unroll
    for (int i = 0; i < 4; i++) {
        int r = r0 + i;
        rid[i] = (r < count) ? list[r] : -1;
    }
#pragma unroll
    for (int c2 = 0; c2 < 2; c2++) {
        int col = (wv * 2 + c2) * 16 + m;
        float bv = bias[col];
#pragma unroll
        for (int i = 0; i < 4; i++)
            if (rid[i] >= 0)
                xb[(size_t)rid[i] * H + col] = f2bf(fmaxf(acc[c2][i] + bv, 0.f));
    }
}

// ---- fused layer 2 + head: agg at centers + GEMM + hadamard + MLP --------
__global__ __launch_bounds__(256) void k_layer2(const unsigned short* xin,
                                                const int2* pairs, const int* cnt,
                                                const unsigned short* Wp,
                                                const float* b2,
                                                const float* l1w, const float* l1b,
                                                const float* l2w, const float* l2b,
                                                float* out) {
    __shared__ unsigned short yt[16][136];
    __shared__ float ct[16][132];
    int t = blockIdx.x;                       // 0..62
    int tid = threadIdx.x, lane = tid & 63, wv = tid >> 6;
    int l2 = lane * 2;

    for (int q = 0; q < 4; q++) {
        int idx = t * 16 + wv * 4 + q;
        float ax = 0.f, ay = 0.f;
        if (idx < 2 * N_GRAPHS) {
            int v = (idx >> 1) * 200 + (idx & 1);
            int n = cnt[v]; if (n > ELL_CAP) n = ELL_CAP;
            const int2* pr = pairs + (size_t)v * ELL_CAP;
            int2 myp = (lane < n) ? pr[lane] : make_int2(0, 0);
            int px = myp.x; float pc = __int_as_float(myp.y);
            float dv = rsqrtf(1.0f + (float)n);
            float sc = dv * dv;
            ushort2 xs = *(const ushort2*)(xin + (size_t)v * H + l2);
            ax = sc * bf2f(xs.x); ay = sc * bf2f(xs.y);
            for (int k = 0; k < n; k++) {
                int s = __shfl(px, k); float c = __shfl(pc, k);
                ushort2 m = *(const ushort2*)(xin + (size_t)s * H + l2);
                ax += c * bf2f(m.x); ay += c * bf2f(m.y);
            }
        }
        ushort2 o; o.x = f2bf(ax); o.y = f2bf(ay);
        *(ushort2*)&yt[wv * 4 + q][l2] = o;
    }
    __syncthreads();

    int m = lane & 15, quad = lane >> 4;
    bf16x8 a0 = *(const bf16x8*)&yt[m][quad * 8];
    bf16x8 a1 = *(const bf16x8*)&yt[m][32 + quad * 8];
    bf16x8 a2 = *(const bf16x8*)&yt[m][64 + quad * 8];
    bf16x8 a3 = *(const bf16x8*)&yt[m][96 + quad * 8];

#pragma unroll
    for (int c2 = 0; c2 < 2; c2++) {
        int c = wv * 2 + c2;
        const unsigned short* bp = Wp + ((size_t)(c * 4) * 64 + lane) * 8;
        bf16x8 b0 = *(const bf16x8*)(bp);
        bf16x8 b1 = *(const bf16x8*)(bp + 64 * 8);
        bf16x8 bb = *(const bf16x8*)(bp + 128 * 8);
        bf16x8 b3 = *(const bf16x8*)(bp + 192 * 8);
        f32x4 a = (f32x4){0.f, 0.f, 0.f, 0.f};
        a = __builtin_amdgcn_mfma_f32_16x16x32_bf16(a0, b0, a, 0, 0, 0);
        a = __builtin_amdgcn_mfma_f32_16x16x32_bf16(a1, b1, a, 0, 0, 0);
        a = __builtin_amdgcn_mfma_f32_16x16x32_bf16(a2, bb, a, 0, 0, 0);
        a = __builtin_amdgcn_mfma_f32_16x16x32_bf16(a3, b3, a, 0, 0, 0);
        int col = c * 16 + m;
        float bv = b2[col];
#pragma unroll
        for (int i = 0; i < 4; i++)
            ct[quad * 4 + i][col] = a[i] + bv;
    }
    __syncthreads();

    // head: 8 graphs per block; 32 threads per graph, 4 output feats each
    int gl = tid >> 5, jq = tid & 31, j4 = jq * 4;
    int g = t * 8 + gl;
    float4 h = *(const float4*)(l1b + j4);
    const float* r0 = &ct[2 * gl][0];
    const float* r1 = &ct[2 * gl + 1][0];
#pragma unroll 4
    for (int k = 0; k < H; k++) {
        float pk = r0[k] * r1[k];
        float4 wv4 = *(const float4*)(l1w + (size_t)k * H + j4);
        h.x += pk * wv4.x; h.y += pk * wv4.y;
        h.z += pk * wv4.z; h.w += pk * wv4.w;
    }
    float4 l2v = *(const float4*)(l2w + j4);
    float s = fmaxf(h.x, 0.f) * l2v.x + fmaxf(h.y, 0.f) * l2v.y +
              fmaxf(h.z, 0.f) * l2v.z + fmaxf(h.w, 0.f) * l2v.w;
#pragma unroll
    for (int d = 16; d > 0; d >>= 1) s += __shfl_xor(s, d, 32);
    if (jq == 0 && g < N_GRAPHS) out[g] = s + l2b[0];
}

extern "C" void kernel_launch(void* const* d_in, const int* in_sizes, int n_in,
                              void* d_out, int out_size, void* d_ws, size_t ws_size,
                              hipStream_t stream) {
    const int*   z    = (const int*)d_in[0];
    const int*   esrc = (const int*)d_in[1];
    const int*   edst = ((const int*)d_in[1]) + N_EDGES;
    const int*   mask = (const int*)d_in[3];
    const float* ztab = (const float*)d_in[4];
    const float* W0   = (const float*)d_in[5];
    const float* b0   = (const float*)d_in[6];
    const float* W1   = (const float*)d_in[7];
    const float* b1   = (const float*)d_in[8];
    const float* W2   = (const float*)d_in[9];
    const float* b2   = (const float*)d_in[10];
    const float* l1w  = (const float*)d_in[11];
    const float* l1b  = (const float*)d_in[12];
    const float* l2w  = (const float*)d_in[13];
    const float* l2b  = (const float*)d_in[14];
    float* out = (float*)d_out;

    char* w = (char*)d_ws;
    size_t o = 0;
    auto carve = [&](size_t bytes) { char* p = w + o; o = (o + bytes + 255) & ~(size_t)255; return p; };
    unsigned short* xb    = (unsigned short*)carve((size_t)N_NODES * H * 2);
    int*            cnt   = (int*)carve((size_t)N_NODES * 4);
    int*            fill  = (int*)carve((size_t)N_NODES * 4);
    int2*           pairs = (int2*)carve((size_t)N_NODES * ELL_CAP * 8);
    unsigned char*  f0    = (unsigned char*)carve(N_NODES);
    unsigned char*  f1    = (unsigned char*)carve(N_NODES);
    int*            list0 = (int*)carve((size_t)N_NODES * 4);
    int*            list1 = (int*)carve((size_t)N_NODES * 4);
    int*            ctrs  = (int*)carve(256);
    unsigned short* Wp    = (unsigned short*)carve((size_t)3 * 16384 * 2);

    const int4* src4  = (const int4*)esrc;
    const int4* dst4  = (const int4*)edst;
    const int4* mask4 = (const int4*)mask;

    k_init       <<<NB, 256, 0, stream>>>(cnt, fill, f0, f1, ctrs);
    k_packw      <<<24, 256, 0, stream>>>(W0, W1, W2, Wp);
    k_scan1      <<<EB, 256, 0, stream>>>(src4, dst4, mask4, cnt, f1);
    k_flag0      <<<EB, 256, 0, stream>>>(src4, dst4, mask4, f1, f0);
    k_fillcompact<<<EB + NB, 256, 0, stream>>>(src4, dst4, mask4, cnt, f0, f1,
                                               fill, pairs, list0, list1, ctrs);

    // layer 0 (N0 rows, worst case 100000), scatter into xb
    k_layerA<<<(N_NODES + 15) / 16, 256, 0, stream>>>(z, ztab, pairs, cnt, list0,
                                                      &ctrs[0], Wp, b0, xb);
    // layer 1 (N1 rows, worst case 33008), in-place gather/scatter on xb
    k_layerB<<<MAXC1 / 16, 256, 0, stream>>>(xb, pairs, cnt, list1, &ctrs[1],
                                             Wp + 16384, b1, xb);
    // layer 2 + pooling + MLP head
    k_layer2<<<NC_ROWS / 16, 256, 0, stream>>>(xb, pairs, cnt, Wp + 32768, b2,
                                               l1w, l1b, l2w, l2b, out);
}